// Round 2
// baseline (1603.684 us; speedup 1.0000x reference)
//
#include <hip/hip_runtime.h>
#include <math.h>

// SchNet fully fused: one workgroup per molecule, all 4 layers + pooling.
// M=2048 molecules x 24 atoms, fully connected: 552 edges/molecule.
// Edge state lives in LDS as MFMA B-fragments (bf16). Zero workspace use.
//
// All GEMMs are computed transposed: D[outFeat][row] = W^T  @  X^T so that the
// MFMA C/D layout (row index on lane&15) directly matches the B-operand layout
// of the next GEMM (verified layouts: A[m=lane&15][k=quad*8+j],
// B[k=quad*8+j][n=lane&15], C col=lane&15 row=quad*4+reg).

#define NTILES 35              // ceil(552/16)
#define LDS_TOTAL 163840       // 160 KiB
#define EA_OFF   0             // 35*4*64*16 = 143360 B : EA B-fragments
#define H_OFF    143360        // 24*128 fp32 (row-swizzled) = 12288 B
#define BIAS_OFF 155648        // e_b1|e_b2|n_b1|n_b2 fp32 = 2048 B
#define POOL_OFF 157696        // 6144 B: coords / x / agg / T1 / z (time-shared)

typedef __attribute__((ext_vector_type(8))) short short8;     // 8 x bf16
typedef __attribute__((ext_vector_type(4))) float floatx4;
typedef __attribute__((ext_vector_type(4))) unsigned short ushort4v;

#define MFMA(A,B,C) __builtin_amdgcn_mfma_f32_16x16x32_bf16((A),(B),(C),0,0,0)

__device__ __forceinline__ short f2bf(float f){     // fp32 -> bf16 RNE
    unsigned u = __float_as_uint(f);
    u += 0x7FFFu + ((u >> 16) & 1u);
    return (short)(u >> 16);
}
__device__ __forceinline__ float bf2f(short s){
    return __uint_as_float(((unsigned)(unsigned short)s) << 16);
}
__device__ __forceinline__ float sspf(float z){     // softplus(z) - log(2)
    return fmaxf(z, 0.f) + __logf(1.f + __expf(-fabsf(z))) - 0.6931471805599453f;
}

// A-operand fragment of W^T for W[K=128][N]: lane j-th element = W[q*32+quad*8+j][a*16+mm]
__device__ __forceinline__ short8 ldwT128(const float* __restrict__ W, int a, int q, int quad, int mm){
    short8 r; int k0 = q*32 + quad*8; int col = a*16 + mm;
    #pragma unroll
    for (int j = 0; j < 8; ++j) r[j] = f2bf(W[(k0 + j)*128 + col]);
    return r;
}
__device__ __forceinline__ short8 ldwT64(const float* __restrict__ W, int a, int q, int quad, int mm){
    short8 r; int k0 = q*32 + quad*8; int col = a*16 + mm;
    #pragma unroll
    for (int j = 0; j < 8; ++j) r[j] = f2bf(W[(k0 + j)*64 + col]);
    return r;
}

// B-operand fragment of h^T (h fp32 in LDS, rows XOR-swizzled by 16B chunk)
__device__ __forceinline__ short8 ld_hT(const float* hb, int dt, int q, int quad, int mm){
    int d = dt*16 + mm; bool val = (d < 24); int da = val ? d : 0;
    int c0 = q*8 + quad*2;
    const char* base = (const char*)hb + da*512;
    floatx4 p0 = *(const floatx4*)(base + ((c0      ^ (da & 15))*16));
    floatx4 p1 = *(const floatx4*)(base + (((c0+1) ^ (da & 15))*16));
    short8 r;
    r[0]=f2bf(p0[0]); r[1]=f2bf(p0[1]); r[2]=f2bf(p0[2]); r[3]=f2bf(p0[3]);
    r[4]=f2bf(p1[0]); r[5]=f2bf(p1[1]); r[6]=f2bf(p1[2]); r[7]=f2bf(p1[3]);
    #pragma unroll
    for (int j = 0; j < 8; ++j) r[j] = val ? r[j] : (short)0;
    return r;
}

extern __shared__ char smem[];

__global__ __launch_bounds__(256, 1) void schnet_fused(
    const int*   __restrict__ charges, const float* __restrict__ coords,
    const float* __restrict__ emb,     const float* __restrict__ wlin,
    const float* __restrict__ e_w1,    const float* __restrict__ e_b1,
    const float* __restrict__ e_w2,    const float* __restrict__ e_b2,
    const float* __restrict__ n_w1,    const float* __restrict__ n_b1,
    const float* __restrict__ n_w2,    const float* __restrict__ n_b2,
    const float* __restrict__ g_w1,    const float* __restrict__ g_b1,
    const float* __restrict__ g_w2,    const float* __restrict__ g_b2,
    float* __restrict__ out)
{
    const int mol  = blockIdx.x;
    const int tid  = threadIdx.x;
    const int wv   = tid >> 6;
    const int lane = tid & 63;
    const int quad = lane >> 4;
    const int mm   = lane & 15;

    char*  ea   = smem + EA_OFF;
    float* hb   = (float*)(smem + H_OFF);
    float* bias = (float*)(smem + BIAS_OFF);
    char*  pool = smem + POOL_OFF;

    // ---- stage coords (pool) + biases ----
    for (int i = tid; i < 72; i += 256) ((float*)pool)[i] = coords[mol*72 + i];
    for (int i = tid; i < 512; i += 256){
        int which = i >> 7, j = i & 127;
        const float* src = (which==0) ? e_b1 : (which==1) ? e_b2 : (which==2) ? n_b1 : n_b2;
        bias[i] = src[j];
    }
    __syncthreads();

    // ---- h init: h[d][:] = emb[charge], row-swizzled fp32 ----
    for (int i = tid; i < 24*32; i += 256){
        int d = i >> 5, c = i & 31;
        int ch = charges[mol*24 + d];
        floatx4 v = ((const floatx4*)emb)[ch*32 + c];
        *(floatx4*)(((char*)hb) + d*512 + ((c ^ (d & 15))*16)) = v;
    }

    // ---- RBF -> EA fragments ----
    {
        const float stepv = 10.0f/127.0f;
        const float coeff = -0.5f/(stepv*stepv);
        const float* cs = (const float*)pool;
        for (int t = wv; t < NTILES; t += 4){
            int e = t*16 + mm; if (e > 551) e = 551;
            int s = e/23, dl = e - s*23; int d = dl + (dl >= s ? 1 : 0);
            float dx = cs[s*3+0]-cs[d*3+0], dy = cs[s*3+1]-cs[d*3+1], dz = cs[s*3+2]-cs[d*3+2];
            float dist = sqrtf(dx*dx + dy*dy + dz*dz);
            #pragma unroll
            for (int q = 0; q < 4; ++q){
                short8 frag;
                #pragma unroll
                for (int j = 0; j < 8; ++j){
                    float g = (float)(q*32 + quad*8 + j)*stepv;
                    float td = dist - g;
                    frag[j] = f2bf(__expf(coeff*td*td));
                }
                *(short8*)(ea + (t*4 + q)*1024 + lane*16) = frag;
            }
        }
    }

    // ---- persistent edge-weight A-fragments (held in VGPRs all kernel) ----
    short8 ew1[8][4], ew2[8][4];
    #pragma unroll
    for (int a = 0; a < 8; ++a)
        #pragma unroll
        for (int q = 0; q < 4; ++q){
            ew1[a][q] = ldwT128(e_w1, a, q, quad, mm);
            ew2[a][q] = ldwT128(e_w2, a, q, quad, mm);
        }
    __syncthreads();

    for (int layer = 0; layer < 4; ++layer){
        // ================= x = h @ wlin  (x -> pool, bf16 [24][128]) =================
        {
            short8 wf[2][4];
            #pragma unroll
            for (int i = 0; i < 2; ++i)
                #pragma unroll
                for (int q = 0; q < 4; ++q) wf[i][q] = ldwT128(wlin, 2*wv + i, q, quad, mm);
            floatx4 acc[2][2];
            #pragma unroll
            for (int i = 0; i < 2; ++i){ acc[i][0] = 0; acc[i][1] = 0; }
            #pragma unroll
            for (int dt = 0; dt < 2; ++dt)
                #pragma unroll
                for (int q = 0; q < 4; ++q){
                    short8 bfr = ld_hT(hb, dt, q, quad, mm);
                    #pragma unroll
                    for (int i = 0; i < 2; ++i) acc[i][dt] = MFMA(wf[i][q], bfr, acc[i][dt]);
                }
            #pragma unroll
            for (int i = 0; i < 2; ++i)
                #pragma unroll
                for (int dt = 0; dt < 2; ++dt){
                    int d = dt*16 + mm;
                    if (d < 24){
                        ushort4v pk;
                        #pragma unroll
                        for (int r = 0; r < 4; ++r) pk[r] = (unsigned short)f2bf(acc[i][dt][r]);
                        *(ushort4v*)(pool + d*256 + ((2*wv + i)*16 + quad*4)*2) = pk;
                    }
                }
        }
        __syncthreads();

        // ================= edge phase: EA = x[s] * (ssp(EA@w1+b1)@w2+b2) =================
        for (int t = wv; t < NTILES; t += 4){
            char* treg = ea + t*4096;               // this tile's 4KB fragment slot
            short8 eaf[4];
            #pragma unroll
            for (int q = 0; q < 4; ++q) eaf[q] = *(short8*)(treg + q*1024 + lane*16);

            floatx4 acc1[8];
            #pragma unroll
            for (int a = 0; a < 8; ++a) acc1[a] = 0;
            #pragma unroll
            for (int q = 0; q < 4; ++q)
                #pragma unroll
                for (int a = 0; a < 8; ++a) acc1[a] = MFMA(ew1[a][q], eaf[q], acc1[a]);

            // bias + ssp, transpose via swizzled scratch in the (dead) tile slot
            #pragma unroll
            for (int a = 0; a < 8; ++a){
                floatx4 bv = *(floatx4*)(bias + a*16 + quad*4);         // e_b1
                ushort4v pk;
                #pragma unroll
                for (int r = 0; r < 4; ++r) pk[r] = (unsigned short)f2bf(sspf(acc1[a][r] + bv[r]));
                *(ushort4v*)(treg + mm*256 + (((a*2 + (quad>>1)) ^ mm)*16) + 8*(quad & 1)) = pk;
            }

            floatx4 acc2[8];
            #pragma unroll
            for (int a = 0; a < 8; ++a) acc2[a] = 0;
            #pragma unroll
            for (int q = 0; q < 4; ++q){
                short8 tf = *(short8*)(treg + mm*256 + (((q*4 + quad) ^ mm)*16));
                #pragma unroll
                for (int a = 0; a < 8; ++a) acc2[a] = MFMA(ew2[a][q], tf, acc2[a]);
            }

            int e = t*16 + mm; int ec = (e > 551) ? 551 : e; int s = ec/23;
            #pragma unroll
            for (int a = 0; a < 8; ++a){
                floatx4 bv = *(floatx4*)(bias + 128 + a*16 + quad*4);   // e_b2
                ushort4v xv = *(ushort4v*)(pool + s*256 + (a*16 + quad*4)*2);
                ushort4v pk;
                #pragma unroll
                for (int r = 0; r < 4; ++r)
                    pk[r] = (unsigned short)f2bf((acc2[a][r] + bv[r]) * bf2f((short)xv[r]));
                // write back in EA fragment layout
                *(ushort4v*)(treg + (a>>1)*1024 + ((((a & 1)*2 + (quad>>1))*16 + mm)*16) + 8*(quad & 1)) = pk;
            }
        }
        __syncthreads();

        // ================= agg stage: agg[d][f] = sum_s EA[e(s,d)][f]  -> pool =================
        {
            int c  = lane & 15;      // 8-feature chunk index
            int sg = lane >> 4;      // source-group
            #pragma unroll
            for (int u = 0; u < 6; ++u){
                int d = wv + 4*u;
                float av[8] = {0,0,0,0,0,0,0,0};
                #pragma unroll
                for (int tt = 0; tt < 6; ++tt){
                    int s2 = sg + 4*tt;
                    int e  = s2*23 + d - (d > s2 ? 1 : 0);
                    float msk = (s2 != d) ? 1.f : 0.f;
                    short8 v = *(short8*)(ea + ((e>>4)*4 + (c>>2))*1024 + (((c & 3)*16 + (e & 15))*16));
                    #pragma unroll
                    for (int j = 0; j < 8; ++j) av[j] += msk * bf2f(v[j]);
                }
                #pragma unroll
                for (int j = 0; j < 8; ++j){
                    av[j] += __shfl_xor(av[j], 32);
                    av[j] += __shfl_xor(av[j], 16);
                }
                if (sg == 0){
                    short8 pk;
                    #pragma unroll
                    for (int j = 0; j < 8; ++j) pk[j] = f2bf(av[j]);
                    *(short8*)(pool + d*256 + ((c ^ (d & 15))*16)) = pk;
                }
            }
        }
        __syncthreads();

        // ================= node MLP: h += ssp(agg@n_w1+b1)@n_w2+b2 =================
        {
            short8 nf[2][4], af[2][4];
            #pragma unroll
            for (int i = 0; i < 2; ++i)
                #pragma unroll
                for (int q = 0; q < 4; ++q) nf[i][q] = ldwT128(n_w1, 2*wv + i, q, quad, mm);
            #pragma unroll
            for (int dt = 0; dt < 2; ++dt){
                int d = dt*16 + mm; bool val = (d < 24); int da = val ? d : 0;
                #pragma unroll
                for (int q = 0; q < 4; ++q){
                    short8 v = *(short8*)(pool + da*256 + (((q*4 + quad) ^ (da & 15))*16));
                    #pragma unroll
                    for (int j = 0; j < 8; ++j) v[j] = val ? v[j] : (short)0;
                    af[dt][q] = v;
                }
            }
            floatx4 accN[2][2];
            #pragma unroll
            for (int i = 0; i < 2; ++i){ accN[i][0] = 0; accN[i][1] = 0; }
            #pragma unroll
            for (int q = 0; q < 4; ++q)
                #pragma unroll
                for (int i = 0; i < 2; ++i)
                    #pragma unroll
                    for (int dt = 0; dt < 2; ++dt) accN[i][dt] = MFMA(nf[i][q], af[dt][q], accN[i][dt]);
            __syncthreads();    // all agg reads done before T1 overwrites pool

            #pragma unroll
            for (int i = 0; i < 2; ++i)
                #pragma unroll
                for (int dt = 0; dt < 2; ++dt){
                    int d = dt*16 + mm;
                    floatx4 bv = *(floatx4*)(bias + 256 + (2*wv + i)*16 + quad*4);  // n_b1
                    if (d < 24){
                        ushort4v pk;
                        #pragma unroll
                        for (int r = 0; r < 4; ++r) pk[r] = (unsigned short)f2bf(sspf(accN[i][dt][r] + bv[r]));
                        *(ushort4v*)(pool + d*256 + ((((2*wv + i)*2 + (quad>>1)) ^ (d & 15))*16) + 8*(quad & 1)) = pk;
                    }
                }
            __syncthreads();

            short8 nf2[2][4], tf[2][4];
            #pragma unroll
            for (int i = 0; i < 2; ++i)
                #pragma unroll
                for (int q = 0; q < 4; ++q) nf2[i][q] = ldwT128(n_w2, 2*wv + i, q, quad, mm);
            #pragma unroll
            for (int dt = 0; dt < 2; ++dt){
                int d = dt*16 + mm; bool val = (d < 24); int da = val ? d : 0;
                #pragma unroll
                for (int q = 0; q < 4; ++q){
                    short8 v = *(short8*)(pool + da*256 + (((q*4 + quad) ^ (da & 15))*16));
                    #pragma unroll
                    for (int j = 0; j < 8; ++j) v[j] = val ? v[j] : (short)0;
                    tf[dt][q] = v;
                }
            }
            floatx4 acc2[2][2];
            #pragma unroll
            for (int i = 0; i < 2; ++i){ acc2[i][0] = 0; acc2[i][1] = 0; }
            #pragma unroll
            for (int q = 0; q < 4; ++q)
                #pragma unroll
                for (int i = 0; i < 2; ++i)
                    #pragma unroll
                    for (int dt = 0; dt < 2; ++dt) acc2[i][dt] = MFMA(nf2[i][q], tf[dt][q], acc2[i][dt]);

            #pragma unroll
            for (int i = 0; i < 2; ++i)
                #pragma unroll
                for (int dt = 0; dt < 2; ++dt){
                    int d = dt*16 + mm;
                    if (d < 24){
                        floatx4 bv = *(floatx4*)(bias + 384 + (2*wv + i)*16 + quad*4);  // n_b2
                        int c0 = (2*wv + i)*4 + quad;      // 16B chunk of f0
                        char* ha = (char*)hb + d*512 + ((c0 ^ (d & 15))*16);
                        floatx4 hv = *(floatx4*)ha;
                        #pragma unroll
                        for (int r = 0; r < 4; ++r) hv[r] += acc2[i][dt][r] + bv[r];
                        *(floatx4*)ha = hv;
                    }
                }
        }
        __syncthreads();
    } // layers

    // ================= graph head: out[mol] = sum_d (ssp(h@g_w1+b1)@g_w2 + b2) =================
    {
        short8 gf[4];
        #pragma unroll
        for (int q = 0; q < 4; ++q) gf[q] = ldwT64(g_w1, wv, q, quad, mm);
        floatx4 acc[2]; acc[0] = 0; acc[1] = 0;
        #pragma unroll
        for (int dt = 0; dt < 2; ++dt)
            #pragma unroll
            for (int q = 0; q < 4; ++q){
                short8 bfr = ld_hT(hb, dt, q, quad, mm);
                acc[dt] = MFMA(gf[q], bfr, acc[dt]);
            }
        floatx4 gbv = *(const floatx4*)(g_b1 + wv*16 + quad*4);
        #pragma unroll
        for (int dt = 0; dt < 2; ++dt){
            int d = dt*16 + mm;
            if (d < 24){
                ushort4v pk;
                #pragma unroll
                for (int r = 0; r < 4; ++r) pk[r] = (unsigned short)f2bf(sspf(acc[dt][r] + gbv[r]));
                *(ushort4v*)(pool + d*128 + (wv*16 + quad*4)*2) = pk;   // z[24][64] bf16
            }
        }
        __syncthreads();
        if (tid < 48){
            int d = tid >> 1, half = tid & 1;
            float v = 0.f;
            const unsigned short* zr = (const unsigned short*)(pool + d*128 + half*64);
            #pragma unroll
            for (int j = 0; j < 32; ++j) v += bf2f((short)zr[j]) * g_w2[half*32 + j];
            v += __shfl_xor(v, 1);
            if (half == 0) ((float*)(pool + 4096))[d] = v;
        }
        __syncthreads();
        if (tid == 0){
            float sum = 0.f;
            #pragma unroll
            for (int d = 0; d < 24; ++d) sum += ((float*)(pool + 4096))[d];
            out[mol] = sum + 24.0f * g_b2[0];
        }
    }
}

extern "C" void kernel_launch(void* const* d_in, const int* in_sizes, int n_in,
                              void* d_out, int out_size, void* d_ws, size_t ws_size,
                              hipStream_t stream) {
    const int*   charges = (const int*)d_in[0];
    const float* coords  = (const float*)d_in[1];
    // d_in[2] node_batch_vec, d_in[3] edge_index: unused (analytic structure)
    const float* emb  = (const float*)d_in[4];
    const float* wlin = (const float*)d_in[5];
    const float* ew1  = (const float*)d_in[6];
    const float* eb1  = (const float*)d_in[7];
    const float* ew2  = (const float*)d_in[8];
    const float* eb2  = (const float*)d_in[9];
    const float* nw1  = (const float*)d_in[10];
    const float* nb1  = (const float*)d_in[11];
    const float* nw2  = (const float*)d_in[12];
    const float* nb2  = (const float*)d_in[13];
    const float* gw1  = (const float*)d_in[14];
    const float* gb1  = (const float*)d_in[15];
    const float* gw2  = (const float*)d_in[16];
    const float* gb2  = (const float*)d_in[17];
    float* out = (float*)d_out;

    hipFuncSetAttribute((const void*)schnet_fused,
                        hipFuncAttributeMaxDynamicSharedMemorySize, LDS_TOTAL);
    schnet_fused<<<2048, 256, LDS_TOTAL, stream>>>(
        charges, coords, emb, wlin, ew1, eb1, ew2, eb2,
        nw1, nb1, nw2, nb2, gw1, gb1, gw2, gb2, out);
}

// Round 3
// 989.860 us; speedup vs baseline: 1.6201x; 1.6201x over previous
//
#include <hip/hip_runtime.h>
#include <math.h>

// SchNet fused, round 3: one workgroup (512 threads, 8 waves) per molecule.
// Fixes vs r2: no persistent weight VGPRs (spill source -> 215MB scratch traffic),
// weights pre-converted to bf16 MFMA A-fragments in d_ws; 2 waves/SIMD; EA subslot
// padding kills the 16-way agg bank conflict; h master in fp32 regs + bf16 mirror.
//
// MFMA 16x16x32 bf16 layouts (HW-verified): A[m=lane&15][k=quad*8+j],
// B[k=quad*8+j][n=lane&15], C/D col(n)=lane&15, row(m)=quad*4+reg.
// All GEMMs transposed: D[outfeat][edge/atom] = W^T @ X^T, so the C-layout matches
// the next GEMM's B-operand (edge/atom index stays on lane&15).

#define NTILES 35              // ceil(552/16) edge tiles
#define SUBSZ  1040            // 1024B frag + 16B pad (de-alias banks for agg)
#define EA_OFF   0             // 35*4 subslots * 1040 = 145600
#define H_OFF    145600        // h mirror bf16 [24][256B], chunk-XOR swizzled
#define BIAS_OFF 151744        // e_b1|e_b2|n_b1|n_b2 fp32 = 2048
#define POOL_OFF 153792        // 6144: coords -> x -> agg -> T1node -> z
#define LDS_TOTAL 159936

#define WLIN_F 0
#define EW1_F  32
#define EW2_F  64
#define NW1_F  96
#define NW2_F  128
#define GW1_F  160

typedef __attribute__((ext_vector_type(8))) short short8;
typedef __attribute__((ext_vector_type(4))) float floatx4;
typedef __attribute__((ext_vector_type(4))) unsigned short ushort4v;

#define MFMA(A,B,C) __builtin_amdgcn_mfma_f32_16x16x32_bf16((A),(B),(C),0,0,0)

__device__ __forceinline__ short f2bf(float f){
    unsigned u = __float_as_uint(f);
    u += 0x7FFFu + ((u >> 16) & 1u);
    return (short)(u >> 16);
}
__device__ __forceinline__ float bf2f(short s){
    return __uint_as_float(((unsigned)(unsigned short)s) << 16);
}
__device__ __forceinline__ float sspf(float z){
    return fmaxf(z, 0.f) + __logf(1.f + __expf(-fabsf(z))) - 0.6931471805599453f;
}
__device__ __forceinline__ short8 ld_ws(const char* __restrict__ ws, int fi, int lane){
    return *(const short8*)(ws + fi*1024 + lane*16);
}
__device__ __forceinline__ short8 ld_bfrag(const char* base, int dt, int q, int quad, int mm){
    int d = dt*16 + mm; bool val = (d < 24); int da = val ? d : 0;
    short8 v = *(const short8*)(base + da*256 + (((q*4 + quad) ^ (da & 15))*16));
    #pragma unroll
    for (int j = 0; j < 8; ++j) v[j] = val ? v[j] : (short)0;
    return v;
}

__global__ __launch_bounds__(64) void prep_frags(
    const float* __restrict__ wlin, const float* __restrict__ ew1,
    const float* __restrict__ ew2,  const float* __restrict__ nw1,
    const float* __restrict__ nw2,  const float* __restrict__ gw1,
    char* __restrict__ ws)
{
    int f = blockIdx.x;                 // 0..175
    int lane = threadIdx.x;
    int quad = lane >> 4, mm = lane & 15;
    const float* W; int ncols, a, q;
    if (f < 160){
        int m = f >> 5, r = f & 31; a = r >> 2; q = r & 3; ncols = 128;
        W = (m==0) ? wlin : (m==1) ? ew1 : (m==2) ? ew2 : (m==3) ? nw1 : nw2;
    } else {
        int r = f - 160; a = r >> 2; q = r & 3; ncols = 64; W = gw1;
    }
    short8 frag;
    #pragma unroll
    for (int j = 0; j < 8; ++j)
        frag[j] = f2bf(W[(q*32 + quad*8 + j)*ncols + a*16 + mm]);
    *(short8*)(ws + f*1024 + lane*16) = frag;
}

extern __shared__ char smem[];

__global__ __launch_bounds__(512, 2) void schnet_fused(
    const int*   __restrict__ charges, const float* __restrict__ coords,
    const float* __restrict__ emb,     const char*  __restrict__ ws,
    const float* __restrict__ e_b1,    const float* __restrict__ e_b2,
    const float* __restrict__ n_b1,    const float* __restrict__ n_b2,
    const float* __restrict__ g_b1,    const float* __restrict__ g_w2,
    const float* __restrict__ g_b2,
    float* __restrict__ out)
{
    const int mol  = blockIdx.x;
    const int tid  = threadIdx.x;
    const int wv   = tid >> 6;
    const int lane = tid & 63;
    const int quad = lane >> 4;
    const int mm   = lane & 15;

    char*  ea   = smem + EA_OFF;
    char*  hmir = smem + H_OFF;
    float* bias = (float*)(smem + BIAS_OFF);
    char*  pool = smem + POOL_OFF;

    if (tid < 72) ((float*)pool)[tid] = coords[mol*72 + tid];
    {
        int which = tid >> 7, j = tid & 127;
        const float* src = (which==0) ? e_b1 : (which==1) ? e_b2 : (which==2) ? n_b1 : n_b2;
        bias[tid] = src[j];
    }

    float hreg[2][4];
    #pragma unroll
    for (int dt = 0; dt < 2; ++dt){
        int d = dt*16 + mm;
        if (d < 24){
            int ch = charges[mol*24 + d];
            floatx4 ev = *(const floatx4*)(emb + (size_t)ch*128 + wv*16 + quad*4);
            ushort4v pk;
            #pragma unroll
            for (int r = 0; r < 4; ++r){ hreg[dt][r] = ev[r]; pk[r] = (unsigned short)f2bf(ev[r]); }
            int cc = wv*2 + (quad >> 1);
            *(ushort4v*)(hmir + d*256 + ((cc ^ (d & 15))*16) + (quad & 1)*8) = pk;
        } else {
            hreg[dt][0]=hreg[dt][1]=hreg[dt][2]=hreg[dt][3]=0.f;
        }
    }
    __syncthreads();

    {   // RBF -> EA B-fragments
        const float stepv = 10.0f/127.0f;
        const float coeff = -0.5f/(stepv*stepv);
        const float* cs = (const float*)pool;
        for (int t = wv; t < NTILES; t += 8){
            int e = t*16 + mm; if (e > 551) e = 551;
            int s = e/23, dl = e - s*23; int d = dl + (dl >= s ? 1 : 0);
            float dx = cs[s*3+0]-cs[d*3+0], dy = cs[s*3+1]-cs[d*3+1], dz = cs[s*3+2]-cs[d*3+2];
            float dist = sqrtf(dx*dx + dy*dy + dz*dz);
            #pragma unroll
            for (int q = 0; q < 4; ++q){
                short8 frag;
                #pragma unroll
                for (int j = 0; j < 8; ++j){
                    float td = dist - (float)(q*32 + quad*8 + j)*stepv;
                    frag[j] = f2bf(__expf(coeff*td*td));
                }
                *(short8*)(ea + (t*4 + q)*SUBSZ + lane*16) = frag;
            }
        }
    }
    __syncthreads();

    for (int layer = 0; layer < 4; ++layer){
        {   // x = h @ wlin -> pool bf16 [24][256B] atom-major
            floatx4 acc[2]; acc[0] = 0; acc[1] = 0;
            #pragma unroll
            for (int q = 0; q < 4; ++q){
                short8 wf = ld_ws(ws, WLIN_F + wv*4 + q, lane);
                #pragma unroll
                for (int dt = 0; dt < 2; ++dt){
                    short8 hf = ld_bfrag(hmir, dt, q, quad, mm);
                    acc[dt] = MFMA(wf, hf, acc[dt]);
                }
            }
            #pragma unroll
            for (int dt = 0; dt < 2; ++dt){
                int d = dt*16 + mm;
                if (d < 24){
                    ushort4v pk;
                    #pragma unroll
                    for (int r = 0; r < 4; ++r) pk[r] = (unsigned short)f2bf(acc[dt][r]);
                    *(ushort4v*)(pool + d*256 + (wv*16 + quad*4)*2) = pk;
                }
            }
        }
        __syncthreads();

        {   // edge phase
            short8 frg[5][4];
            bool tv[5]; int tl[5];
            #pragma unroll
            for (int ti = 0; ti < 5; ++ti){
                int t = wv + 8*ti; tv[ti] = (t < NTILES); tl[ti] = tv[ti] ? t : wv;
            }
            #pragma unroll
            for (int ti = 0; ti < 5; ++ti)
                #pragma unroll
                for (int q = 0; q < 4; ++q)
                    frg[ti][q] = *(const short8*)(ea + (tl[ti]*4 + q)*SUBSZ + lane*16);

            #pragma unroll 1
            for (int a = 0; a < 8; ++a){            // GEMM1 -> T1 in B-frag layout
                floatx4 acc[5];
                #pragma unroll
                for (int ti = 0; ti < 5; ++ti) acc[ti] = 0;
                #pragma unroll
                for (int q = 0; q < 4; ++q){
                    short8 wf = ld_ws(ws, EW1_F + a*4 + q, lane);
                    #pragma unroll
                    for (int ti = 0; ti < 5; ++ti) acc[ti] = MFMA(wf, frg[ti][q], acc[ti]);
                }
                floatx4 bv = *(floatx4*)(bias + a*16 + quad*4);
                int qp = a >> 1, qq = (a & 1)*2 + (quad >> 1), off8 = (quad & 1)*8;
                #pragma unroll
                for (int ti = 0; ti < 5; ++ti){
                    if (tv[ti]){
                        ushort4v pk;
                        #pragma unroll
                        for (int r = 0; r < 4; ++r) pk[r] = (unsigned short)f2bf(sspf(acc[ti][r] + bv[r]));
                        *(ushort4v*)(ea + (tl[ti]*4 + qp)*SUBSZ + (qq*16 + mm)*16 + off8) = pk;
                    }
                }
            }
            #pragma unroll
            for (int ti = 0; ti < 5; ++ti)
                #pragma unroll
                for (int q = 0; q < 4; ++q)
                    frg[ti][q] = *(const short8*)(ea + (tl[ti]*4 + q)*SUBSZ + lane*16);

            #pragma unroll 1
            for (int a = 0; a < 8; ++a){            // GEMM2 -> EA back in B-frag layout
                floatx4 acc[5];
                #pragma unroll
                for (int ti = 0; ti < 5; ++ti) acc[ti] = 0;
                #pragma unroll
                for (int q = 0; q < 4; ++q){
                    short8 wf = ld_ws(ws, EW2_F + a*4 + q, lane);
                    #pragma unroll
                    for (int ti = 0; ti < 5; ++ti) acc[ti] = MFMA(wf, frg[ti][q], acc[ti]);
                }
                floatx4 bv = *(floatx4*)(bias + 128 + a*16 + quad*4);
                int qp = a >> 1, qq = (a & 1)*2 + (quad >> 1), off8 = (quad & 1)*8;
                #pragma unroll
                for (int ti = 0; ti < 5; ++ti){
                    if (tv[ti]){
                        int e = tl[ti]*16 + mm; if (e > 551) e = 551;
                        int s = e / 23;
                        ushort4v xv = *(const ushort4v*)(pool + s*256 + (a*16 + quad*4)*2);
                        ushort4v pk;
                        #pragma unroll
                        for (int r = 0; r < 4; ++r)
                            pk[r] = (unsigned short)f2bf((acc[ti][r] + bv[r]) * bf2f((short)xv[r]));
                        *(ushort4v*)(ea + (tl[ti]*4 + qp)*SUBSZ + (qq*16 + mm)*16 + off8) = pk;
                    }
                }
            }
        }
        __syncthreads();

        {   // agg
            int c = lane & 15, sg = lane >> 4;
            #pragma unroll
            for (int u = 0; u < 3; ++u){
                int d = wv + 8*u;
                float av[8] = {0,0,0,0,0,0,0,0};
                #pragma unroll
                for (int tt = 0; tt < 6; ++tt){
                    int s2 = sg + 4*tt;
                    int e  = s2*23 + d - (d > s2 ? 1 : 0);
                    float msk = (s2 != d) ? 1.f : 0.f;
                    short8 v = *(const short8*)(ea + ((e >> 4)*4 + (c >> 2))*SUBSZ
                                                + (((c & 3)*16 + (e & 15))*16));
                    #pragma unroll
                    for (int j = 0; j < 8; ++j) av[j] += msk * bf2f(v[j]);
                }
                #pragma unroll
                for (int j = 0; j < 8; ++j){
                    av[j] += __shfl_xor(av[j], 32);
                    av[j] += __shfl_xor(av[j], 16);
                }
                if (sg == 0){
                    short8 pk;
                    #pragma unroll
                    for (int j = 0; j < 8; ++j) pk[j] = f2bf(av[j]);
                    *(short8*)(pool + d*256 + ((c ^ (d & 15))*16)) = pk;
                }
            }
        }
        __syncthreads();

        {   // node MLP
            floatx4 acc[2]; acc[0] = 0; acc[1] = 0;
            #pragma unroll
            for (int q = 0; q < 4; ++q){
                short8 wf = ld_ws(ws, NW1_F + wv*4 + q, lane);
                #pragma unroll
                for (int dt = 0; dt < 2; ++dt){
                    short8 af = ld_bfrag(pool, dt, q, quad, mm);
                    acc[dt] = MFMA(wf, af, acc[dt]);
                }
            }
            __syncthreads();
            {
                floatx4 bv = *(floatx4*)(bias + 256 + wv*16 + quad*4);
                int cc = wv*2 + (quad >> 1), off8 = (quad & 1)*8;
                #pragma unroll
                for (int dt = 0; dt < 2; ++dt){
                    int d = dt*16 + mm;
                    if (d < 24){
                        ushort4v pk;
                        #pragma unroll
                        for (int r = 0; r < 4; ++r) pk[r] = (unsigned short)f2bf(sspf(acc[dt][r] + bv[r]));
                        *(ushort4v*)(pool + d*256 + ((cc ^ (d & 15))*16) + off8) = pk;
                    }
                }
            }
            __syncthreads();
            floatx4 acc2[2]; acc2[0] = 0; acc2[1] = 0;
            #pragma unroll
            for (int q = 0; q < 4; ++q){
                short8 wf = ld_ws(ws, NW2_F + wv*4 + q, lane);
                #pragma unroll
                for (int dt = 0; dt < 2; ++dt){
                    short8 tf = ld_bfrag(pool, dt, q, quad, mm);
                    acc2[dt] = MFMA(wf, tf, acc2[dt]);
                }
            }
            floatx4 b2 = *(floatx4*)(bias + 384 + wv*16 + quad*4);
            int cc = wv*2 + (quad >> 1), off8 = (quad & 1)*8;
            #pragma unroll
            for (int dt = 0; dt < 2; ++dt){
                int d = dt*16 + mm;
                if (d < 24){
                    ushort4v pk;
                    #pragma unroll
                    for (int r = 0; r < 4; ++r){
                        hreg[dt][r] += acc2[dt][r] + b2[r];
                        pk[r] = (unsigned short)f2bf(hreg[dt][r]);
                    }
                    *(ushort4v*)(hmir + d*256 + ((cc ^ (d & 15))*16) + off8) = pk;
                }
            }
        }
        __syncthreads();
    }

    {   // graph head
        int a = wv & 3, dtt = wv >> 2;
        floatx4 acc = 0;
        #pragma unroll
        for (int q = 0; q < 4; ++q){
            short8 gf = ld_ws(ws, GW1_F + a*4 + q, lane);
            short8 hf = ld_bfrag(hmir, dtt, q, quad, mm);
            acc = MFMA(gf, hf, acc);
        }
        int d = dtt*16 + mm;
        floatx4 gb = *(const floatx4*)(g_b1 + a*16 + quad*4);
        if (d < 24){
            ushort4v pk;
            #pragma unroll
            for (int r = 0; r < 4; ++r) pk[r] = (unsigned short)f2bf(sspf(acc[r] + gb[r]));
            *(ushort4v*)(pool + d*128 + (a*16 + quad*4)*2) = pk;
        }
        __syncthreads();
        if (tid < 48){
            int dd = tid >> 1, half = tid & 1;
            float v = 0.f;
            const unsigned short* zr = (const unsigned short*)(pool + dd*128 + half*64);
            #pragma unroll
            for (int j = 0; j < 32; ++j) v += bf2f((short)zr[j]) * g_w2[half*32 + j];
            v += __shfl_xor(v, 1);
            if (half == 0) ((float*)(pool + 4096))[dd] = v;
        }
        __syncthreads();
        if (tid == 0){
            float sum = 0.f;
            #pragma unroll
            for (int dd = 0; dd < 24; ++dd) sum += ((float*)(pool + 4096))[dd];
            out[mol] = sum + 24.0f * g_b2[0];
        }
    }
}

extern "C" void kernel_launch(void* const* d_in, const int* in_sizes, int n_in,
                              void* d_out, int out_size, void* d_ws, size_t ws_size,
                              hipStream_t stream) {
    const int*   charges = (const int*)d_in[0];
    const float* coords  = (const float*)d_in[1];
    const float* emb  = (const float*)d_in[4];
    const float* wlin = (const float*)d_in[5];
    const float* ew1  = (const float*)d_in[6];
    const float* eb1  = (const float*)d_in[7];
    const float* ew2  = (const float*)d_in[8];
    const float* eb2  = (const float*)d_in[9];
    const float* nw1  = (const float*)d_in[10];
    const float* nb1  = (const float*)d_in[11];
    const float* nw2  = (const float*)d_in[12];
    const float* nb2  = (const float*)d_in[13];
    const float* gw1  = (const float*)d_in[14];
    const float* gb1  = (const float*)d_in[15];
    const float* gw2  = (const float*)d_in[16];
    const float* gb2  = (const float*)d_in[17];
    float* out = (float*)d_out;
    char* ws = (char*)d_ws;                 // 176 KB of bf16 weight fragments

    prep_frags<<<176, 64, 0, stream>>>(wlin, ew1, ew2, nw1, nw2, gw1, ws);

    hipFuncSetAttribute((const void*)schnet_fused,
                        hipFuncAttributeMaxDynamicSharedMemorySize, LDS_TOTAL);
    schnet_fused<<<2048, 512, LDS_TOTAL, stream>>>(
        charges, coords, emb, ws, eb1, eb2, nb1, nb2, gb1, gw2, gb2, out);
}